// Round 9
// baseline (153.981 us; speedup 1.0000x reference)
//
#include <hip/hip_runtime.h>

// PointPillarsScatter: canvas[b, :, y, x] = feat[p, :], last-writer-wins.
// Phase 1: memset winner; Phase 2: winner[b,y,x] = max(p)+1 via atomicMax;
// Phase 3: LDS-transpose gather (exact R6 champion geometry: 128 cells/block,
// rows[128][65], 33KB LDS, 4 blocks/CU), with ONE change: normal through-L2
// stores instead of nontemporal. A/B isolates the NT flag: the rocclr fill
// hits 6.7 TB/s on this same buffer with through-L2 stores (full-line
// write-combining); NT may be issuing sub-line HBM bursts.

constexpr int HH  = 496;
constexpr int WW  = 432;
constexpr int CC  = 64;
constexpr int HWp = HH * WW;   // 214272
constexpr int W4  = WW / 4;    // 108
constexpr int QPB   = 32;      // quads per block
constexpr int CELLS = QPB * 4; // 128
constexpr int PAD   = 65;      // LDS row stride in floats

typedef float v4f __attribute__((ext_vector_type(4)));

// Zero-initialized device global: the "feature row" of empty cells (fallback).
__device__ float g_zero_row[CC];

__global__ void k_winner(const int* __restrict__ coords, int* __restrict__ winner,
                         int wstride, int P) {
    int p = blockIdx.x * blockDim.x + threadIdx.x;
    if (p >= P) return;
    int4 c4 = reinterpret_cast<const int4*>(coords)[p];  // (b, z, y, x)
    atomicMax(&winner[c4.x * wstride + c4.z * WW + c4.w], p + 1);
}

__global__ __launch_bounds__(256) void k_gather_lds(
        const float* __restrict__ feat, const int* __restrict__ winner,
        float* __restrict__ out, int blocksPerBatch) {
    __shared__ float rows[CELLS * PAD];   // 33,280 B

    const int bb       = blockIdx.x / blocksPerBatch;
    const int cellbase = (blockIdx.x % blocksPerBatch) * (QPB * 4);
    const int t   = threadIdx.x;
    const int grp = t >> 4;   // 0..15 (row group in load phase)
    const int ln  = t & 15;   // 0..15 (lane within row)

    const int* wbase = winner + bb * HWp + cellbase;

    // --- load phase: 8 rounds x 16 rows, 256B coalesced per row ---
    #pragma unroll
    for (int r = 0; r < 8; ++r) {
        int row = r * 16 + grp;
        int w = wbase[row];                       // broadcast within 16-lane group
        v4f v = {0.0f, 0.0f, 0.0f, 0.0f};
        if (w > 0)
            v = *reinterpret_cast<const v4f*>(feat + (size_t)(w - 1) * CC + ln * 4);
        *reinterpret_cast<v4f*>(&rows[row * PAD + ln * 4]) = v;
    }
    __syncthreads();

    // --- store phase: 8 rounds x 8 channels, 32 lanes per channel ---
    const int qv = t & 31;    // which v4f within the channel's 512B span
    const int cg = t >> 5;    // 0..7
    float* obase = out + (size_t)bb * CC * HWp + cellbase;
    #pragma unroll
    for (int r = 0; r < 8; ++r) {
        int c = r * 8 + cg;
        v4f s;
        s.x = rows[(qv * 4 + 0) * PAD + c];
        s.y = rows[(qv * 4 + 1) * PAD + c];
        s.z = rows[(qv * 4 + 2) * PAD + c];
        s.w = rows[(qv * 4 + 3) * PAD + c];
        *reinterpret_cast<v4f*>(obase + (size_t)c * HWp + qv * 4) = s;
    }
}

// ---- fallback gather (ws too small): winner lives in out's c=0 plane.
// Thread-per-cell, reads its own winner quad exactly once before overwriting.
__global__ __launch_bounds__(256) void k_gather_cells(
        const float* __restrict__ feat, const int* __restrict__ winner,
        int wstride, float* __restrict__ out, int total) {
    int t = blockIdx.x * blockDim.x + threadIdx.x;
    if (t >= total) return;
    int x4 = t % W4;  int r = t / W4;
    int y  = r % HH;  int bb = r / HH;
    const int4 win = *reinterpret_cast<const int4*>(
        &winner[bb * wstride + y * WW + x4 * 4]);
    const float* f0 = (win.x > 0) ? feat + (size_t)(win.x - 1) * CC : g_zero_row;
    const float* f1 = (win.y > 0) ? feat + (size_t)(win.y - 1) * CC : g_zero_row;
    const float* f2 = (win.z > 0) ? feat + (size_t)(win.z - 1) * CC : g_zero_row;
    const float* f3 = (win.w > 0) ? feat + (size_t)(win.w - 1) * CC : g_zero_row;
    float* ob = out + ((size_t)bb * CC * HH + y) * WW + x4 * 4;
    #pragma unroll 4
    for (int cq = 0; cq < CC / 4; ++cq) {
        v4f a = *reinterpret_cast<const v4f*>(f0 + cq * 4);
        v4f b = *reinterpret_cast<const v4f*>(f1 + cq * 4);
        v4f c = *reinterpret_cast<const v4f*>(f2 + cq * 4);
        v4f d = *reinterpret_cast<const v4f*>(f3 + cq * 4);
        float* o = ob + (size_t)cq * 4 * HWp;
        v4f s0 = {a.x, b.x, c.x, d.x};
        v4f s1 = {a.y, b.y, c.y, d.y};
        v4f s2 = {a.z, b.z, c.z, d.z};
        v4f s3 = {a.w, b.w, c.w, d.w};
        *reinterpret_cast<v4f*>(o)           = s0;
        *reinterpret_cast<v4f*>(o + HWp)     = s1;
        *reinterpret_cast<v4f*>(o + 2 * HWp) = s2;
        *reinterpret_cast<v4f*>(o + 3 * HWp) = s3;
    }
}

extern "C" void kernel_launch(void* const* d_in, const int* in_sizes, int n_in,
                              void* d_out, int out_size, void* d_ws, size_t ws_size,
                              hipStream_t stream) {
    const float* feat   = (const float*)d_in[0];
    const int*   coords = (const int*)d_in[1];
    float*       out    = (float*)d_out;

    const int P = in_sizes[0] / CC;        // 96000
    const int B = out_size / (CC * HWp);   // 8

    const size_t winner_bytes = (size_t)B * HWp * sizeof(int);

    if (ws_size >= winner_bytes) {
        // --- primary: winner array in workspace ---
        int* winner = (int*)d_ws;
        hipMemsetAsync(winner, 0, winner_bytes, stream);
        k_winner<<<(P + 255) / 256, 256, 0, stream>>>(coords, winner, HWp, P);
        const int blocksPerBatch = (HH * W4) / QPB;   // 53568/32 = 1674
        const int nblocks = B * blocksPerBatch;       // 13392
        k_gather_lds<<<nblocks, 256, 0, stream>>>(feat, winner, out, blocksPerBatch);
    } else {
        // --- fallback: winner in out's c=0 plane, thread-per-cell gather ---
        for (int b = 0; b < B; ++b)
            hipMemsetAsync(out + (size_t)b * CC * HWp, 0,
                           (size_t)HWp * sizeof(int), stream);
        k_winner<<<(P + 255) / 256, 256, 0, stream>>>(
            coords, (int*)out, CC * HWp, P);
        const int total = B * HH * W4;
        k_gather_cells<<<(total + 255) / 256, 256, 0, stream>>>(
            feat, (int*)out, CC * HWp, out, total);
    }
}

// Round 10
// 98.658 us; speedup vs baseline: 1.5607x; 1.5607x over previous
//
#include <hip/hip_runtime.h>

// PointPillarsScatter: canvas[b, :, y, x] = feat[p, :], last-writer-wins.
// Phase 1: memset winner; Phase 2: winner[b,y,x] = max(p)+1 via atomicMax;
// Phase 3: channel-group pipelined gather. Block owns 1024 consecutive cells
// (global cell index over B*H*W), loops over 16 groups of 4 channels:
//   - winner held in 4 registers/thread (loaded once, reused all groups)
//   - fill: occupied cells load a 16B feat slice, write channel-major into
//     stg[4][1028] (bank (4c+cell)%32 -> 2 lanes/bank = free)
//   - store: each wave = one channel, 4 contiguous ds_read_b128 + 4KB
//     contiguous nontemporal store run
// vs R6: run length 512B -> 4KB per channel AND occupancy 16 -> 32 waves/CU
// (LDS 33KB -> 16.4KB). Attacks DRAM row-buffer thrash from ~65k concurrent
// short write streams. NT stores kept (R9: through-L2 = 154us disaster).

constexpr int HH  = 496;
constexpr int WW  = 432;
constexpr int CC  = 64;
constexpr int HWp = HH * WW;    // 214272
constexpr int W4  = WW / 4;     // 108
constexpr int CELLS = 1024;     // cells per block (primary gather)
constexpr int PADR  = 1028;     // LDS row stride in floats (16B-aligned, +4)
// R6 fallback geometry
constexpr int QPB   = 32;
constexpr int CELLS6 = 128;
constexpr int PAD6   = 65;

typedef float v4f __attribute__((ext_vector_type(4)));

__device__ float g_zero_row[CC];

__global__ void k_winner(const int* __restrict__ coords, int* __restrict__ winner,
                         int wstride, int P) {
    int p = blockIdx.x * blockDim.x + threadIdx.x;
    if (p >= P) return;
    int4 c4 = reinterpret_cast<const int4*>(coords)[p];  // (b, z, y, x)
    atomicMax(&winner[c4.x * wstride + c4.z * WW + c4.w], p + 1);
}

// Primary gather: requires (B*HWp) % CELLS == 0.
__global__ __launch_bounds__(256) void k_gather_pipe(
        const float* __restrict__ feat, const int* __restrict__ winner,
        float* __restrict__ out) {
    __shared__ float stg[4 * PADR];   // 16,448 B -> 8 blocks/CU

    const int g0    = blockIdx.x * CELLS;
    const int bb    = g0 / HWp;             // batch of first cell
    const int bound = (bb + 1) * HWp;       // first cell of next batch
    const int t   = threadIdx.x;
    const int wid = t >> 6;                 // wave id 0..3 = channel in group
    const int qv  = t & 63;

    // winner for this block's 1024 cells, in registers (coalesced loads)
    int wreg[4];
    const float* fp[4];
    #pragma unroll
    for (int k = 0; k < 4; ++k) {
        wreg[k] = winner[g0 + t + 256 * k];
        fp[k] = feat + (size_t)(wreg[k] - 1) * CC;   // valid only if wreg>0
    }

    for (int grp = 0; grp < 16; ++grp) {
        // --- fill: channel-major staging, zeros for empty cells ---
        #pragma unroll
        for (int k = 0; k < 4; ++k) {
            int cell = t + 256 * k;
            v4f v = {0.0f, 0.0f, 0.0f, 0.0f};
            if (wreg[k] > 0)
                v = *reinterpret_cast<const v4f*>(fp[k] + grp * 4);
            stg[0 * PADR + cell] = v.x;
            stg[1 * PADR + cell] = v.y;
            stg[2 * PADR + cell] = v.z;
            stg[3 * PADR + cell] = v.w;
        }
        __syncthreads();

        // --- store: wave 'wid' handles channel c; 4KB contiguous NT run ---
        const int c = grp * 4 + wid;
        #pragma unroll
        for (int k = 0; k < 4; ++k) {
            int cell = (k * 64 + qv) * 4;
            int g = g0 + cell;
            int b = (g >= bound) ? bb + 1 : bb;
            int i = g - b * HWp;
            v4f s = *reinterpret_cast<const v4f*>(&stg[wid * PADR + cell]);
            __builtin_nontemporal_store(
                s, reinterpret_cast<v4f*>(out + ((size_t)b * CC + c) * HWp + i));
        }
        __syncthreads();
    }
}

// R6-geometry gather (general-shape path, winner in ws).
__global__ __launch_bounds__(256) void k_gather_lds(
        const float* __restrict__ feat, const int* __restrict__ winner,
        float* __restrict__ out, int blocksPerBatch) {
    __shared__ float rows[CELLS6 * PAD6];

    const int bb       = blockIdx.x / blocksPerBatch;
    const int cellbase = (blockIdx.x % blocksPerBatch) * (QPB * 4);
    const int t   = threadIdx.x;
    const int grp = t >> 4;
    const int ln  = t & 15;

    const int* wbase = winner + bb * HWp + cellbase;

    #pragma unroll
    for (int r = 0; r < 8; ++r) {
        int row = r * 16 + grp;
        int w = wbase[row];
        v4f v = {0.0f, 0.0f, 0.0f, 0.0f};
        if (w > 0)
            v = *reinterpret_cast<const v4f*>(feat + (size_t)(w - 1) * CC + ln * 4);
        *reinterpret_cast<v4f*>(&rows[row * PAD6 + ln * 4]) = v;
    }
    __syncthreads();

    const int qv = t & 31;
    const int cg = t >> 5;
    float* obase = out + (size_t)bb * CC * HWp + cellbase;
    #pragma unroll
    for (int r = 0; r < 8; ++r) {
        int c = r * 8 + cg;
        v4f s;
        s.x = rows[(qv * 4 + 0) * PAD6 + c];
        s.y = rows[(qv * 4 + 1) * PAD6 + c];
        s.z = rows[(qv * 4 + 2) * PAD6 + c];
        s.w = rows[(qv * 4 + 3) * PAD6 + c];
        __builtin_nontemporal_store(
            s, reinterpret_cast<v4f*>(obase + (size_t)c * HWp + qv * 4));
    }
}

// Last-resort fallback (ws too small): winner lives in out's c=0 plane.
__global__ __launch_bounds__(256) void k_gather_cells(
        const float* __restrict__ feat, const int* __restrict__ winner,
        int wstride, float* __restrict__ out, int total) {
    int t = blockIdx.x * blockDim.x + threadIdx.x;
    if (t >= total) return;
    int x4 = t % W4;  int r = t / W4;
    int y  = r % HH;  int bb = r / HH;
    const int4 win = *reinterpret_cast<const int4*>(
        &winner[bb * wstride + y * WW + x4 * 4]);
    const float* f0 = (win.x > 0) ? feat + (size_t)(win.x - 1) * CC : g_zero_row;
    const float* f1 = (win.y > 0) ? feat + (size_t)(win.y - 1) * CC : g_zero_row;
    const float* f2 = (win.z > 0) ? feat + (size_t)(win.z - 1) * CC : g_zero_row;
    const float* f3 = (win.w > 0) ? feat + (size_t)(win.w - 1) * CC : g_zero_row;
    float* ob = out + ((size_t)bb * CC * HH + y) * WW + x4 * 4;
    #pragma unroll 4
    for (int cq = 0; cq < CC / 4; ++cq) {
        v4f a = *reinterpret_cast<const v4f*>(f0 + cq * 4);
        v4f b = *reinterpret_cast<const v4f*>(f1 + cq * 4);
        v4f c = *reinterpret_cast<const v4f*>(f2 + cq * 4);
        v4f d = *reinterpret_cast<const v4f*>(f3 + cq * 4);
        float* o = ob + (size_t)cq * 4 * HWp;
        v4f s0 = {a.x, b.x, c.x, d.x};
        v4f s1 = {a.y, b.y, c.y, d.y};
        v4f s2 = {a.z, b.z, c.z, d.z};
        v4f s3 = {a.w, b.w, c.w, d.w};
        __builtin_nontemporal_store(s0, reinterpret_cast<v4f*>(o));
        __builtin_nontemporal_store(s1, reinterpret_cast<v4f*>(o + HWp));
        __builtin_nontemporal_store(s2, reinterpret_cast<v4f*>(o + 2 * HWp));
        __builtin_nontemporal_store(s3, reinterpret_cast<v4f*>(o + 3 * HWp));
    }
}

extern "C" void kernel_launch(void* const* d_in, const int* in_sizes, int n_in,
                              void* d_out, int out_size, void* d_ws, size_t ws_size,
                              hipStream_t stream) {
    const float* feat   = (const float*)d_in[0];
    const int*   coords = (const int*)d_in[1];
    float*       out    = (float*)d_out;

    const int P = in_sizes[0] / CC;        // 96000
    const int B = out_size / (CC * HWp);   // 8
    const int totalCells = B * HWp;        // 1,714,176

    const size_t winner_bytes = (size_t)totalCells * sizeof(int);

    if (ws_size >= winner_bytes) {
        int* winner = (int*)d_ws;
        hipMemsetAsync(winner, 0, winner_bytes, stream);
        k_winner<<<(P + 255) / 256, 256, 0, stream>>>(coords, winner, HWp, P);
        if (totalCells % CELLS == 0) {
            k_gather_pipe<<<totalCells / CELLS, 256, 0, stream>>>(
                feat, winner, out);
        } else {
            const int blocksPerBatch = (HH * W4) / QPB;
            k_gather_lds<<<B * blocksPerBatch, 256, 0, stream>>>(
                feat, winner, out, blocksPerBatch);
        }
    } else {
        for (int b = 0; b < B; ++b)
            hipMemsetAsync(out + (size_t)b * CC * HWp, 0,
                           (size_t)HWp * sizeof(int), stream);
        k_winner<<<(P + 255) / 256, 256, 0, stream>>>(
            coords, (int*)out, CC * HWp, P);
        const int total = B * HH * W4;
        k_gather_cells<<<(total + 255) / 256, 256, 0, stream>>>(
            feat, (int*)out, CC * HWp, out, total);
    }
}